// Round 1
// baseline (31.674 us; speedup 1.0000x reference)
//
#include <hip/hip_runtime.h>
#include <math.h>

#define NUM_AUG 10
#define S_PAIRS 500
#define P 256

// c_pair = 256/((20+1e-8)*0.01), c_single = 256/((10+1e-8)*0.01)
__device__ __constant__ const float C_PAIR = (float)(256.0 / ((20.0 + 1e-8) * 0.01));
__device__ __constant__ const float C_SING = (float)(256.0 / ((10.0 + 1e-8) * 0.01));

__global__ __launch_bounds__(256) void pair_logdet_kernel(
    const float* __restrict__ X,
    const int* __restrict__ pairs,
    float* __restrict__ out2 /* [S_PAIRS][2]: ld_pair, ld_i+ld_j */) {
  __shared__ float rows[20][P + 1];  // +1 pad: break stride-256 bank alias
  __shared__ float G[20][21];
  __shared__ float M0[20][21];
  __shared__ float M1[10][11];
  __shared__ float M2[10][11];
  __shared__ float res[3];

  const int s = blockIdx.x;
  const int tid = threadIdx.x;
  const int i0 = pairs[2 * s + 0] * NUM_AUG;
  const int j0 = pairs[2 * s + 1] * NUM_AUG;

  // ---- load 20 rows (contiguous in X) into LDS, coalesced ----
  for (int e = tid; e < 20 * P; e += 256) {
    int r = e >> 8;
    int c = e & 255;
    int gr = (r < 10) ? (i0 + r) : (j0 + (r - 10));
    rows[r][c] = X[gr * P + c];
  }
  __syncthreads();

  // ---- Gram: upper triangle (210 entries), one dot per thread ----
  if (tid < 210) {
    int a = 0, rem = tid;
    while (rem >= 20 - a) { rem -= 20 - a; ++a; }
    int b = a + rem;
    float acc = 0.f;
#pragma unroll 8
    for (int c = 0; c < P; ++c) acc = fmaf(rows[a][c], rows[b][c], acc);
    G[a][b] = acc;
    G[b][a] = acc;
  }
  __syncthreads();

  // ---- build M0 = I20 + c_pair*G ; M1/M2 = I10 + c_sing*G-blocks ----
  for (int e = tid; e < 400; e += 256) {
    int a = e / 20, b = e % 20;
    M0[a][b] = C_PAIR * G[a][b] + (a == b ? 1.f : 0.f);
  }
  if (tid < 100) {
    int a = tid / 10, b = tid % 10;
    M1[a][b] = C_SING * G[a][b] + (a == b ? 1.f : 0.f);
    M2[a][b] = C_SING * G[a + 10][b + 10] + (a == b ? 1.f : 0.f);
  }
  __syncthreads();

  // ---- three wave-parallel Choleskys: wave0->M0(20), wave1->M1(10), wave2->M2(10) ----
  const int wave = tid >> 6;
  const int lane = tid & 63;
  for (int j = 0; j < 20; ++j) {
    if (lane == 0) {
      if (wave == 0) {
        float ss = M0[j][j];
        for (int k = 0; k < j; ++k) ss -= M0[j][k] * M0[j][k];
        M0[j][j] = sqrtf(ss);
      } else if (wave == 1 && j < 10) {
        float ss = M1[j][j];
        for (int k = 0; k < j; ++k) ss -= M1[j][k] * M1[j][k];
        M1[j][j] = sqrtf(ss);
      } else if (wave == 2 && j < 10) {
        float ss = M2[j][j];
        for (int k = 0; k < j; ++k) ss -= M2[j][k] * M2[j][k];
        M2[j][j] = sqrtf(ss);
      }
    }
    __syncthreads();
    int i = j + 1 + lane;
    if (wave == 0 && i < 20) {
      float ss = M0[i][j];
      for (int k = 0; k < j; ++k) ss -= M0[i][k] * M0[j][k];
      M0[i][j] = ss / M0[j][j];
    } else if (wave == 1 && j < 10 && i < 10) {
      float ss = M1[i][j];
      for (int k = 0; k < j; ++k) ss -= M1[i][k] * M1[j][k];
      M1[i][j] = ss / M1[j][j];
    } else if (wave == 2 && j < 10 && i < 10) {
      float ss = M2[i][j];
      for (int k = 0; k < j; ++k) ss -= M2[i][k] * M2[j][k];
      M2[i][j] = ss / M2[j][j];
    }
    __syncthreads();
  }

  // ---- logdet = 2*sum(log(diag(L))) ----
  if (lane == 0 && wave < 3) {
    float ld = 0.f;
    const int n = (wave == 0) ? 20 : 10;
    for (int j = 0; j < n; ++j) {
      float d = (wave == 0) ? M0[j][j] : (wave == 1) ? M1[j][j] : M2[j][j];
      ld += logf(d);
    }
    res[wave] = 2.f * ld;
  }
  __syncthreads();
  if (tid == 0) {
    out2[2 * s + 0] = res[0];
    out2[2 * s + 1] = res[1] + res[2];
  }
}

__global__ __launch_bounds__(256) void reduce_kernel(
    const float* __restrict__ out2, float* __restrict__ out) {
  __shared__ float sh[4][2];
  const int tid = threadIdx.x;
  float sp = 0.f, sij = 0.f;
  for (int s = tid; s < S_PAIRS; s += 256) {
    sp += out2[2 * s + 0];
    sij += out2[2 * s + 1];
  }
  for (int off = 32; off; off >>= 1) {
    sp += __shfl_down(sp, off);
    sij += __shfl_down(sij, off);
  }
  const int wave = tid >> 6, lane = tid & 63;
  if (lane == 0) { sh[wave][0] = sp; sh[wave][1] = sij; }
  __syncthreads();
  if (tid == 0) {
    float tp = 0.f, tij = 0.f;
    for (int w = 0; w < 4; ++w) { tp += sh[w][0]; tij += sh[w][1]; }
    const float mp = tp / (float)S_PAIRS;
    const float mij = tij / (float)S_PAIRS;
    const float ortho = mp - 0.5f * mij;
    out[0] = -0.01f * ortho;  // total_loss_empi = GAM3 * -ortho
    out[1] = mp;              // discrimn_loss_empi
    out[2] = mij;             // compress_loss_empi
    out[3] = ortho;           // compress_loss_empi_ortho
  }
}

extern "C" void kernel_launch(void* const* d_in, const int* in_sizes, int n_in,
                              void* d_out, int out_size, void* d_ws, size_t ws_size,
                              hipStream_t stream) {
  const float* X = (const float*)d_in[0];
  // d_in[1] is y (int64) — unused by the loss values.
  const int* pairs = (const int*)d_in[2];
  float* out = (float*)d_out;
  float* ws = (float*)d_ws;  // [S_PAIRS][2]

  pair_logdet_kernel<<<S_PAIRS, 256, 0, stream>>>(X, pairs, ws);
  reduce_kernel<<<1, 256, 0, stream>>>(ws, out);
}

// Round 2
// 15.387 us; speedup vs baseline: 2.0585x; 2.0585x over previous
//
#include <hip/hip_runtime.h>
#include <math.h>

#define NUM_AUG 10
#define S_PAIRS 500
#define P 256

typedef __attribute__((ext_vector_type(8))) short bf16x8;
typedef __attribute__((ext_vector_type(16))) float f32x16;

// c_pair = 256/((20+1e-8)*0.01), c_single = 256/((10+1e-8)*0.01)
#define C_PAIR ((float)(256.0 / ((20.0 + 1e-8) * 0.01)))
#define C_SING ((float)(256.0 / ((10.0 + 1e-8) * 0.01)))

__device__ __forceinline__ unsigned short f2bf(float f) {
  unsigned u = __float_as_uint(f);
  unsigned r = (u + 0x7fffu + ((u >> 16) & 1u)) >> 16;  // RNE
  return (unsigned short)r;
}

// One wave (64 threads) per pair. No __syncthreads-dependent multi-wave logic.
__global__ __launch_bounds__(64) void pair_kernel(
    const float* __restrict__ X,
    const int* __restrict__ pairs,
    float* __restrict__ out2 /* [S_PAIRS][2] */) {
  // S staged as bf16, 32 rows x 512 bytes, XOR-swizzled: phys = row*512 + (cb ^ ((row&15)<<4))
  __shared__ uint4 Sb4[32 * 512 / 16];
  __shared__ float G[20][21];
  char* Sb = (char*)Sb4;

  const int s = blockIdx.x;
  const int lane = threadIdx.x;  // 0..63
  const int i0 = pairs[2 * s + 0] * NUM_AUG;
  const int j0 = pairs[2 * s + 1] * NUM_AUG;

  // ---- load 20 rows of X (f32), convert to bf16, stage swizzled ----
#pragma unroll
  for (int r = 0; r < 20; ++r) {
    const int gr = (r < 10) ? (i0 + r) : (j0 + (r - 10));
    const float4 v = *((const float4*)(X + (size_t)gr * P) + lane);
    uint2 w;
    w.x = (unsigned)f2bf(v.x) | ((unsigned)f2bf(v.y) << 16);
    w.y = (unsigned)f2bf(v.z) | ((unsigned)f2bf(v.w) << 16);
    const int off = r * 512 + ((lane * 8) ^ ((r & 15) << 4));
    *(uint2*)(Sb + off) = w;
  }
  __syncthreads();

  // ---- G = S * S^T via 32x32x16 bf16 MFMA; a_frag == b_frag ----
  // A[m][k]: lane = m + 32*(k/8), holds k = (lane>>5)*8 .. +8 contiguous.
  const int row = lane & 31;
  const int kg = lane >> 5;
  f32x16 acc;
#pragma unroll
  for (int i = 0; i < 16; ++i) acc[i] = 0.f;
#pragma unroll
  for (int kk = 0; kk < 16; ++kk) {
    const int cb = kk * 32 + kg * 16;  // byte col of this 8-elem k-slice
    const bf16x8 f = *(const bf16x8*)(Sb + row * 512 + (cb ^ ((row & 15) << 4)));
    acc = __builtin_amdgcn_mfma_f32_32x32x16_bf16(f, f, acc, 0, 0, 0);
  }
  // C/D layout (m74/m101): col = lane&31, row = (reg&3) + 8*(reg>>2) + 4*(lane>>5)
#pragma unroll
  for (int rg = 0; rg < 16; ++rg) {
    const int grow = (rg & 3) + 8 * (rg >> 2) + 4 * kg;
    const int gcol = row;
    if (grow < 20 && gcol < 20) G[grow][gcol] = acc[rg];
  }
  __syncthreads();

  // ---- three register Choleskys in one wave, shuffle-based, no barriers ----
  // lanes 0-31: M0 = I20 + C_PAIR*G          (n=20)
  // lanes 32-47: M1 = I10 + C_SING*G[0:10]   (n=10)
  // lanes 48-63: M2 = I10 + C_SING*G[10:20]  (n=10)
  const int grp = (lane < 32) ? 0 : (lane < 48) ? 1 : 2;
  const int base = (grp == 0) ? 0 : (grp == 1) ? 32 : 48;
  const int li = lane - base;
  const int n = (grp == 0) ? 20 : 10;
  const float cf = (grp == 0) ? C_PAIR : C_SING;
  const int r0 = (grp == 2) ? 10 : 0;

  float a[20];
#pragma unroll
  for (int k = 0; k < 20; ++k) {
    float g = 0.f;
    if (li < n && k < n) g = G[r0 + li][r0 + k];
    a[k] = cf * g + ((li == k) ? 1.f : 0.f);
  }

  float ld_acc = 0.f;
#pragma unroll
  for (int j = 0; j < 20; ++j) {
    const float dj = __shfl(a[j], base + j, 64);
    const float Ljj = sqrtf(dj);
    const float inv = 1.0f / Ljj;
    const float Lij = a[j] * inv;  // valid for li >= j; garbage elsewhere (never consumed)
    if (li == j && j < n) ld_acc += logf(Ljj);
#pragma unroll
    for (int k = j + 1; k < 20; ++k) {
      const float ck = __shfl(Lij, base + k, 64);
      if (k < n && li >= k) a[k] = fmaf(-Lij, ck, a[k]);
    }
  }

  // ---- reduce: ld_pair over lanes<32, ld_i+ld_j over lanes>=32 ----
  float vp = (lane < 32) ? ld_acc : 0.f;
  float vs = (lane >= 32) ? ld_acc : 0.f;
#pragma unroll
  for (int m = 1; m < 64; m <<= 1) {
    vp += __shfl_xor(vp, m, 64);
    vs += __shfl_xor(vs, m, 64);
  }
  if (lane == 0) {
    out2[2 * s + 0] = 2.f * vp;
    out2[2 * s + 1] = 2.f * vs;
  }
}

__global__ __launch_bounds__(256) void reduce_kernel(
    const float* __restrict__ out2, float* __restrict__ out) {
  __shared__ float sh[4][2];
  const int tid = threadIdx.x;
  float sp = 0.f, sij = 0.f;
  for (int s = tid; s < S_PAIRS; s += 256) {
    sp += out2[2 * s + 0];
    sij += out2[2 * s + 1];
  }
  for (int off = 32; off; off >>= 1) {
    sp += __shfl_down(sp, off);
    sij += __shfl_down(sij, off);
  }
  const int wave = tid >> 6, lane = tid & 63;
  if (lane == 0) { sh[wave][0] = sp; sh[wave][1] = sij; }
  __syncthreads();
  if (tid == 0) {
    float tp = 0.f, tij = 0.f;
    for (int w = 0; w < 4; ++w) { tp += sh[w][0]; tij += sh[w][1]; }
    const float mp = tp / (float)S_PAIRS;
    const float mij = tij / (float)S_PAIRS;
    const float ortho = mp - 0.5f * mij;
    out[0] = -0.01f * ortho;  // total_loss_empi = GAM3 * -ortho
    out[1] = mp;              // discrimn_loss_empi
    out[2] = mij;             // compress_loss_empi
    out[3] = ortho;           // compress_loss_empi_ortho
  }
}

extern "C" void kernel_launch(void* const* d_in, const int* in_sizes, int n_in,
                              void* d_out, int out_size, void* d_ws, size_t ws_size,
                              hipStream_t stream) {
  const float* X = (const float*)d_in[0];
  // d_in[1] is y (int64) — unused by the loss values.
  const int* pairs = (const int*)d_in[2];
  float* out = (float*)d_out;
  float* ws = (float*)d_ws;  // [S_PAIRS][2]

  pair_kernel<<<S_PAIRS, 64, 0, stream>>>(X, pairs, ws);
  reduce_kernel<<<1, 256, 0, stream>>>(ws, out);
}